// Round 5
// baseline (509.452 us; speedup 1.0000x reference)
//
#include <hip/hip_runtime.h>
#include <hip/hip_bf16.h>
#include <stdint.h>

#define TLEN 64
#define BSZ 32
#define SLEN 64
#define HS 1024
#define VOC 32000
#define NROW (TLEN*BSZ)   // 2048
#define C_CONST_F 0.1712209f

// GEMM geometry: 256x256 tile, 4-slot B-only K-pipeline, BK=32 per slot, A direct from L2
#define BM 256
#define BN 256
#define BKT 32
#define NKT (HS/BKT)          // 32 K-tiles
#define SLOT_B 16384          // 16KB B slot

typedef __attribute__((ext_vector_type(8))) short short8;
typedef __attribute__((ext_vector_type(4))) float f32x4;

static __device__ __forceinline__ ushort f2bf(float f) {
    uint32_t u = __builtin_bit_cast(uint32_t, f);
    uint32_t r = (u + 0x7fffu + ((u >> 16) & 1u)) >> 16;
    return (ushort)r;
}
static __device__ __forceinline__ float bf2f(ushort u) {
    uint32_t v = ((uint32_t)u) << 16;
    return __builtin_bit_cast(float, v);
}
static __device__ __forceinline__ void async16(const void* g, void* lds) {
    __builtin_amdgcn_global_load_lds(
        (const __attribute__((address_space(1))) void*)g,
        (__attribute__((address_space(3))) void*)lds, 16, 0, 0);
}
static __device__ __forceinline__ int swz12(int e) { return e ^ (((e >> 4) & 15) << 1); }

// ---------------- copy gate ---------------------------------------------------------
__global__ __launch_bounds__(256) void gate_kernel(const float* __restrict__ hidden,
                                                   const float* __restrict__ w_copy,
                                                   const float* __restrict__ b_copy,
                                                   float* __restrict__ cp) {
    int wid = threadIdx.x >> 6, lane = threadIdx.x & 63;
    int row = blockIdx.x * 4 + wid;
    const float* h = hidden + (size_t)row * HS;
    float acc = 0.f;
    for (int i = 0; i < 4; ++i) {
        int off = (i * 64 + lane) * 4;
        float4 a = *(const float4*)(h + off);
        float4 w = *(const float4*)(w_copy + off);
        acc += a.x * w.x + a.y * w.y + a.z * w.z + a.w * w.w;
    }
    for (int m = 32; m >= 1; m >>= 1) acc += __shfl_xor(acc, m, 64);
    if (lane == 0) cp[row] = 1.f / (1.f + expf(-(acc + b_copy[0])));
}

// ---------------- copy attention (f32 for precision) --------------------------------
__global__ __launch_bounds__(256) void attn_kernel(const float* __restrict__ hidden,
                                                   const float* __restrict__ context,
                                                   const int* __restrict__ src,
                                                   const float* __restrict__ cp,
                                                   float* __restrict__ p_c) {
    int row = blockIdx.x;           // t*BSZ + b
    int b = row & (BSZ - 1);
    int tid = threadIdx.x, wid = tid >> 6, lane = tid & 63;
    __shared__ float hrow[HS];
    __shared__ float sc[SLEN];
    *(float4*)(hrow + tid * 4) = *(const float4*)(hidden + (size_t)row * HS + tid * 4);
    __syncthreads();
    for (int j = 0; j < 16; ++j) {
        int s = wid * 16 + j;
        const float* c = context + ((size_t)s * BSZ + b) * HS;
        float acc = 0.f;
        for (int i = 0; i < 4; ++i) {
            int off = (i * 64 + lane) * 4;
            float4 cv = *(const float4*)(c + off);
            float4 hv = *(const float4*)(hrow + off);
            acc += cv.x * hv.x + cv.y * hv.y + cv.z * hv.z + cv.w * hv.w;
        }
        for (int m = 32; m >= 1; m >>= 1) acc += __shfl_xor(acc, m, 64);
        if (lane == 0) sc[s] = acc;
    }
    __syncthreads();
    if (tid < SLEN) {
        float v = sc[tid];
        if (src[b * SLEN + tid] == 0) v = -INFINITY;   // PAD mask
        float m = v;
        for (int k = 32; k >= 1; k >>= 1) m = fmaxf(m, __shfl_xor(m, k, 64));
        float e = expf(v - m);
        float ssum = e;
        for (int k = 32; k >= 1; k >>= 1) ssum += __shfl_xor(ssum, k, 64);
        p_c[row * SLEN + tid] = (e / ssum) * cp[row];
    }
}

// ---------------- f32 -> bf16 conversion --------------------------------------------
__global__ __launch_bounds__(256) void cvt_kernel(const float* __restrict__ in,
                                                  ushort* __restrict__ out, int n4) {
    int i = blockIdx.x * blockDim.x + threadIdx.x;
    if (i >= n4) return;
    float4 v = ((const float4*)in)[i];
    ushort4 o;
    o.x = f2bf(v.x); o.y = f2bf(v.y); o.z = f2bf(v.z); o.w = f2bf(v.w);
    ((ushort4*)out)[i] = o;
}

// ---------------- main GEMM: logits = A(2048x1024) * B(32000x1024)^T + b_gen --------
// 256x256 tile, 8 waves (2Mx4N). B staged through 4x16KB LDS slots (XOR-swizzled,
// counted vmcnt, 1 barrier/tile). A (4MB, L2-resident) read directly into registers
// per tile (loaded for kt+1 after MFMA(kt)). Epilogue: partials + bf16 logit store.
template <bool BF16L>
__global__ __launch_bounds__(512, 2) void gemm_kernel(const ushort* __restrict__ A,
                                                      const ushort* __restrict__ B,
                                                      const float* __restrict__ b_gen,
                                                      void* __restrict__ logits,
                                                      float* __restrict__ partials /*[NROW][500][2]*/) {
    __shared__ ushort sAB[65536];   // 128KB: first 64KB = 4 B-slots; all reused by epilogue

    // bijective XCD-chunk swizzle: 1000 blocks = 8 xcds x 125
    int orig = blockIdx.x;
    int wg = (orig & 7) * 125 + (orig >> 3);
    int mIdx = wg & 7;            // 8 m-tiles
    int nIdx = wg >> 3;           // 125 n-tiles
    int m0 = mIdx * BM, n0 = nIdx * BN;
    int tid = threadIdx.x, wid = tid >> 6, lane = tid & 63;
    int wm = (wid >> 2) * 128, wn = (wid & 3) * 64;
    int lr = lane & 15, lg = lane >> 4;

    // B staging sources (k-invariant). chunk s holds row=s>>2, kc=(s&3)^((row>>1)&3)
    const ushort* gB[2];
    uint32_t ldsOffB[2];
    #pragma unroll
    for (int j = 0; j < 2; ++j) {
        int s = j * 512 + tid;
        int row = s >> 2;
        int kc = (s & 3) ^ ((row >> 1) & 3);
        gB[j] = B + (size_t)(n0 + row) * HS + kc * 8;
        ldsOffB[j] = (uint32_t)((j * 512 + wid * 64) * 16);   // wave-uniform dest
    }

    // B frag-read byte offsets within a slot
    uint32_t kcs  = (uint32_t)((lg ^ ((lr >> 1) & 3)) * 16);
    uint32_t offBb = (uint32_t)(wn + lr) * 64 + kcs;          // + nb*1024

    // A row pointers: direct per-lane global reads (L1/L2-resident)
    const ushort* aRow[8];
    #pragma unroll
    for (int mb = 0; mb < 8; ++mb)
        aRow[mb] = A + (size_t)(m0 + wm + mb * 16 + lr) * HS + lg * 8;

    f32x4 acc[8][4];
    #pragma unroll
    for (int m = 0; m < 8; ++m)
        #pragma unroll
        for (int n = 0; n < 4; ++n) acc[m][n] = f32x4{0.f, 0.f, 0.f, 0.f};

#define STAGE_B(KT)                                                        \
    {                                                                      \
        char* sd = (char*)sAB + ((KT) & 3) * SLOT_B;                       \
        int k0s = (KT) * BKT;                                              \
        async16(gB[0] + k0s, sd + ldsOffB[0]);                             \
        async16(gB[1] + k0s, sd + ldsOffB[1]);                             \
    }

    // prologue — VMEM issue order pinned: S0, A0, S1, S2 (ledger: vmcnt(12) forces S0)
    short8 av[8];
    STAGE_B(0);
    __builtin_amdgcn_sched_barrier(0);
    #pragma unroll
    for (int mb = 0; mb < 8; ++mb) av[mb] = *(const short8*)(aRow[mb]);
    __builtin_amdgcn_sched_barrier(0);
    STAGE_B(1);
    STAGE_B(2);
    asm volatile("s_waitcnt vmcnt(12)" ::: "memory");
    asm volatile("s_barrier" ::: "memory");

    // main loop: 1 barrier + 1 counted vmcnt per K-tile.
    // Ledger (steady): queue = [S(kt+2), A(kt), S(kt+3)] -> vmcnt(2) forces A(kt)+S(kt+2),
    // leaves S(kt+3) in flight. Stage-gate for slot kt+1 is subsumed (forced one tile early,
    // before this wave's barrier). Tail (kt>=NKT-3): no stage -> vmcnt(0) (A-only, L2-fast).
    for (int kt = 0; kt < NKT; ++kt) {
        const char* sl = (const char*)sAB + (kt & 3) * SLOT_B;
        short8 bv[4];
        #pragma unroll
        for (int nb = 0; nb < 4; ++nb)
            bv[nb] = *(const short8*)(sl + offBb + nb * 1024);
        if (kt < NKT - 3) {
            STAGE_B(kt + 3);
            asm volatile("s_waitcnt vmcnt(2)" ::: "memory");
        } else {
            asm volatile("s_waitcnt vmcnt(0)" ::: "memory");
        }
        asm volatile("s_waitcnt lgkmcnt(0)" ::: "memory");
        __builtin_amdgcn_sched_barrier(0);
        __builtin_amdgcn_s_setprio(1);
        #pragma unroll
        for (int mb = 0; mb < 8; ++mb)
            #pragma unroll
            for (int nb = 0; nb < 4; ++nb)
                acc[mb][nb] = __builtin_amdgcn_mfma_f32_16x16x32_bf16(av[mb], bv[nb],
                                                                     acc[mb][nb], 0, 0, 0);
        __builtin_amdgcn_s_setprio(0);
        if (kt < NKT - 1) {
            const ushort* ak = (const ushort*)((const char*)0 + (kt + 1) * (BKT * 2));
            #pragma unroll
            for (int mb = 0; mb < 8; ++mb)
                av[mb] = *(const short8*)(aRow[mb] + (kt + 1) * BKT);
            (void)ak;
        }
        asm volatile("s_barrier" ::: "memory");
    }
#undef STAGE_B

    // ---- epilogue (loop's final barrier synced all waves; LDS reusable) ----
    float bg[4];
    #pragma unroll
    for (int nb = 0; nb < 4; ++nb) bg[nb] = b_gen[n0 + wn + nb * 16 + lr];
    int chunk = nIdx * 4 + (wid & 3);         // 500 chunks of 64 cols
    ushort* stile = sAB + wid * 8192;         // 128x64 bf16 per-wave repack region (16KB)

    #pragma unroll
    for (int mb = 0; mb < 8; ++mb) {
        #pragma unroll
        for (int r = 0; r < 4; ++r) {
            int rl = mb * 16 + lg * 4 + r;    // row within wave tile (0..127)
            int row = m0 + wm + rl;
            float v[4];
            float mx = -INFINITY;
            #pragma unroll
            for (int nb = 0; nb < 4; ++nb) {
                v[nb] = acc[mb][nb][r] + bg[nb];
                mx = fmaxf(mx, v[nb]);
            }
            if (BF16L) {
                #pragma unroll
                for (int nb = 0; nb < 4; ++nb) {
                    int cl = nb * 16 + lr;
                    int slot_w = (cl >> 3) ^ (rl & 7);
                    stile[rl * 64 + slot_w * 8 + (cl & 7)] = f2bf(v[nb]);
                }
            } else {
                float* outp = (float*)logits;
                #pragma unroll
                for (int nb = 0; nb < 4; ++nb)
                    outp[(size_t)row * VOC + n0 + wn + nb * 16 + lr] = v[nb];
            }
            for (int k = 8; k >= 1; k >>= 1) mx = fmaxf(mx, __shfl_xor(mx, k, 16));
            float se = 0.f;
            #pragma unroll
            for (int nb = 0; nb < 4; ++nb) se += __expf(v[nb] - mx);
            for (int k = 8; k >= 1; k >>= 1) se += __shfl_xor(se, k, 16);
            if (lr == 0) {
                float2 pv; pv.x = mx; pv.y = se;
                *(float2*)(partials + ((size_t)row * 500 + chunk) * 2) = pv;
            }
        }
    }
    if (BF16L) {
        ushort* Lbf = (ushort*)logits;
        #pragma unroll
        for (int rep = 0; rep < 16; ++rep) {
            int idx = rep * 64 + lane;
            int rl = idx >> 3, c8 = idx & 7;
            int slot_r = c8 ^ (rl & 7);
            short8 val = *(const short8*)(stile + rl * 64 + slot_r * 8);
            ushort* dst = Lbf + (size_t)(m0 + wm + rl) * VOC + n0 + wn + c8 * 8;
            *(short8*)dst = val;
        }
    }
}

// ---------------- combine per-chunk partials ----------------------------------------
__global__ __launch_bounds__(256) void reduce_kernel(const float* __restrict__ partials,
                                                     float* __restrict__ Ms,
                                                     float* __restrict__ Ss) {
    int wid = threadIdx.x >> 6, lane = threadIdx.x & 63;
    int row = blockIdx.x * 4 + wid;
    float m = -INFINITY, s = 0.f;
    for (int c = lane; c < 500; c += 64) {
        float2 p = *(const float2*)(partials + ((size_t)row * 500 + c) * 2);
        float nm = fmaxf(m, p.x);
        s = s * __expf(m - nm) + p.y * __expf(p.x - nm);
        m = nm;
    }
    for (int k = 32; k >= 1; k >>= 1) {
        float om = __shfl_xor(m, k, 64), os = __shfl_xor(s, k, 64);
        float nm = fmaxf(m, om);
        s = s * __expf(m - nm) + os * __expf(om - nm);
        m = nm;
    }
    if (lane == 0) { Ms[row] = m; Ss[row] = s; }
}

// ---------------- finalize: softmax scale, scatter-add p_c, log ---------------------
template <bool BF16L>
__global__ __launch_bounds__(256) void finalize_kernel(const int* __restrict__ src,
                                                       const float* __restrict__ p_c,
                                                       const float* __restrict__ cp,
                                                       const float* __restrict__ Ms,
                                                       const float* __restrict__ Ss,
                                                       const void* __restrict__ logits,
                                                       float* __restrict__ out) {
    int row = blockIdx.y;
    int c0 = blockIdx.x * 4096;
    int b = row & (BSZ - 1);
    __shared__ float addv[4096];
    int tid = threadIdx.x;
    for (int i = tid; i < 4096; i += 256) addv[i] = 0.f;
    __syncthreads();
    if (tid < SLEN) {
        int v = src[b * SLEN + tid];
        if (v >= c0 && v < c0 + 4096)
            atomicAdd(&addv[swz12(v - c0)], p_c[row * SLEN + tid]);
    }
    __syncthreads();
    int col = c0 + tid * 16;
    if (col >= VOC) return;
    float M = Ms[row];
    float g = (1.f - cp[row]) / Ss[row];
    float L[16];
    if (BF16L) {
        const ushort* lb = (const ushort*)logits + (size_t)row * VOC + col;
        short8 a = *(const short8*)lb;
        short8 c = *(const short8*)(lb + 8);
        for (int i = 0; i < 8; ++i) { L[i] = bf2f((ushort)a[i]); L[8 + i] = bf2f((ushort)c[i]); }
    } else {
        const float* lf = (const float*)logits + (size_t)row * VOC + col;
        for (int i = 0; i < 4; ++i) {
            float4 v = *(const float4*)(lf + i * 4);
            L[i * 4 + 0] = v.x; L[i * 4 + 1] = v.y; L[i * 4 + 2] = v.z; L[i * 4 + 3] = v.w;
        }
    }
    float res[16];
    for (int i = 0; i < 16; ++i) {
        float p = __expf(L[i] - M) * g + addv[swz12(tid * 16 + i)];
        res[i] = __logf(p) + C_CONST_F;
    }
    float* op = out + (size_t)row * VOC + col;
    for (int i = 0; i < 4; ++i) {
        float4 v;
        v.x = res[i * 4 + 0]; v.y = res[i * 4 + 1]; v.z = res[i * 4 + 2]; v.w = res[i * 4 + 3];
        *(float4*)(op + i * 4) = v;
    }
}

extern "C" void kernel_launch(void* const* d_in, const int* in_sizes, int n_in,
                              void* d_out, int out_size, void* d_ws, size_t ws_size,
                              hipStream_t stream) {
    const float* hidden  = (const float*)d_in[0];
    const float* context = (const float*)d_in[1];
    const int*   src     = (const int*)d_in[2];
    const float* W_gen   = (const float*)d_in[3];
    const float* b_gen   = (const float*)d_in[4];
    const float* w_copy  = (const float*)d_in[5];
    const float* b_copy  = (const float*)d_in[6];
    float* out = (float*)d_out;
    char* ws = (char*)d_ws;

    float*  cp       = (float*)(ws);                    // 8 KB
    float*  p_c      = (float*)(ws + 8192);             // 512 KB
    float*  Ms       = (float*)(ws + 532480);
    float*  Ss       = (float*)(ws + 540672);
    float*  partials = (float*)(ws + 548864);           // 8.192 MB
    ushort* Abf      = (ushort*)(ws + 8740864);         // 4 MB
    ushort* Wbf      = (ushort*)(ws + 12935168);        // 65.5 MB -> ends 78471168
    ushort* Lbf      = (ushort*)(ws + 78471168);        // 131 MB  -> ends 209543168
    const size_t NEED_BF16 = 209543168;

    gate_kernel<<<NROW / 4, 256, 0, stream>>>(hidden, w_copy, b_copy, cp);
    attn_kernel<<<NROW, 256, 0, stream>>>(hidden, context, src, cp, p_c);
    cvt_kernel<<<(NROW * HS / 4) / 256, 256, 0, stream>>>(hidden, Abf, NROW * HS / 4);
    cvt_kernel<<<(VOC * HS / 4) / 256, 256, 0, stream>>>(W_gen, Wbf, VOC * HS / 4);

    int ggrid = (NROW / BM) * (VOC / BN);   // 8 * 125 = 1000
    dim3 fgrid(8, NROW);
    if (ws_size >= NEED_BF16) {
        gemm_kernel<true><<<ggrid, 512, 0, stream>>>(Abf, Wbf, b_gen, Lbf, partials);
        reduce_kernel<<<NROW / 4, 256, 0, stream>>>(partials, Ms, Ss);
        finalize_kernel<true><<<fgrid, 256, 0, stream>>>(src, p_c, cp, Ms, Ss, Lbf, out);
    } else {
        gemm_kernel<false><<<ggrid, 512, 0, stream>>>(Abf, Wbf, b_gen, out, partials);
        reduce_kernel<<<NROW / 4, 256, 0, stream>>>(partials, Ms, Ss);
        finalize_kernel<false><<<fgrid, 256, 0, stream>>>(src, p_c, cp, Ms, Ss, out, out);
    }
}

// Round 6
// 385.560 us; speedup vs baseline: 1.3213x; 1.3213x over previous
//
#include <hip/hip_runtime.h>
#include <hip/hip_bf16.h>
#include <stdint.h>

#define TLEN 64
#define BSZ 32
#define SLEN 64
#define HS 1024
#define VOC 32000
#define NROW (TLEN*BSZ)   // 2048
#define C_CONST_F 0.1712209f

// GEMM geometry: 128x128 tile, 4 waves, 4-slot K-pipeline, BK=32/slot, 64KB LDS
// -> 2 independent blocks/CU (m97/m114 cross-block overlap mechanism)
#define BM 128
#define BN 128
#define BKT 32
#define NKT (HS/BKT)          // 32 K-tiles
#define SLOT_BYTES 16384      // A 8KB + B 8KB
#define B_REGION 8192         // byte offset of B within slot

typedef __attribute__((ext_vector_type(8))) short short8;
typedef __attribute__((ext_vector_type(4))) float f32x4;

static __device__ __forceinline__ ushort f2bf(float f) {
    uint32_t u = __builtin_bit_cast(uint32_t, f);
    uint32_t r = (u + 0x7fffu + ((u >> 16) & 1u)) >> 16;
    return (ushort)r;
}
static __device__ __forceinline__ float bf2f(ushort u) {
    uint32_t v = ((uint32_t)u) << 16;
    return __builtin_bit_cast(float, v);
}
static __device__ __forceinline__ void async16(const void* g, void* lds) {
    __builtin_amdgcn_global_load_lds(
        (const __attribute__((address_space(1))) void*)g,
        (__attribute__((address_space(3))) void*)lds, 16, 0, 0);
}
static __device__ __forceinline__ int swz12(int e) { return e ^ (((e >> 4) & 15) << 1); }

// ---------------- copy gate ---------------------------------------------------------
__global__ __launch_bounds__(256) void gate_kernel(const float* __restrict__ hidden,
                                                   const float* __restrict__ w_copy,
                                                   const float* __restrict__ b_copy,
                                                   float* __restrict__ cp) {
    int wid = threadIdx.x >> 6, lane = threadIdx.x & 63;
    int row = blockIdx.x * 4 + wid;
    const float* h = hidden + (size_t)row * HS;
    float acc = 0.f;
    for (int i = 0; i < 4; ++i) {
        int off = (i * 64 + lane) * 4;
        float4 a = *(const float4*)(h + off);
        float4 w = *(const float4*)(w_copy + off);
        acc += a.x * w.x + a.y * w.y + a.z * w.z + a.w * w.w;
    }
    for (int m = 32; m >= 1; m >>= 1) acc += __shfl_xor(acc, m, 64);
    if (lane == 0) cp[row] = 1.f / (1.f + expf(-(acc + b_copy[0])));
}

// ---------------- copy attention (f32 for precision) --------------------------------
__global__ __launch_bounds__(256) void attn_kernel(const float* __restrict__ hidden,
                                                   const float* __restrict__ context,
                                                   const int* __restrict__ src,
                                                   const float* __restrict__ cp,
                                                   float* __restrict__ p_c) {
    int row = blockIdx.x;           // t*BSZ + b
    int b = row & (BSZ - 1);
    int tid = threadIdx.x, wid = tid >> 6, lane = tid & 63;
    __shared__ float hrow[HS];
    __shared__ float sc[SLEN];
    *(float4*)(hrow + tid * 4) = *(const float4*)(hidden + (size_t)row * HS + tid * 4);
    __syncthreads();
    for (int j = 0; j < 16; ++j) {
        int s = wid * 16 + j;
        const float* c = context + ((size_t)s * BSZ + b) * HS;
        float acc = 0.f;
        for (int i = 0; i < 4; ++i) {
            int off = (i * 64 + lane) * 4;
            float4 cv = *(const float4*)(c + off);
            float4 hv = *(const float4*)(hrow + off);
            acc += cv.x * hv.x + cv.y * hv.y + cv.z * hv.z + cv.w * hv.w;
        }
        for (int m = 32; m >= 1; m >>= 1) acc += __shfl_xor(acc, m, 64);
        if (lane == 0) sc[s] = acc;
    }
    __syncthreads();
    if (tid < SLEN) {
        float v = sc[tid];
        if (src[b * SLEN + tid] == 0) v = -INFINITY;   // PAD mask
        float m = v;
        for (int k = 32; k >= 1; k >>= 1) m = fmaxf(m, __shfl_xor(m, k, 64));
        float e = expf(v - m);
        float ssum = e;
        for (int k = 32; k >= 1; k >>= 1) ssum += __shfl_xor(ssum, k, 64);
        p_c[row * SLEN + tid] = (e / ssum) * cp[row];
    }
}

// ---------------- f32 -> bf16 conversion --------------------------------------------
__global__ __launch_bounds__(256) void cvt_kernel(const float* __restrict__ in,
                                                  ushort* __restrict__ out, int n4) {
    int i = blockIdx.x * blockDim.x + threadIdx.x;
    if (i >= n4) return;
    float4 v = ((const float4*)in)[i];
    ushort4 o;
    o.x = f2bf(v.x); o.y = f2bf(v.y); o.z = f2bf(v.z); o.w = f2bf(v.w);
    ((ushort4*)out)[i] = o;
}

// ---------------- main GEMM: logits = A(2048x1024) * B(32000x1024)^T + b_gen --------
// 128x128 tile, 4 waves (2Mx2N, 64x64/wave). 4-slot LDS pipeline (XOR-swizzled,
// counted vmcnt, 1 barrier/tile — R3-verified schedule), 64KB LDS -> 2 blocks/CU.
template <bool BF16L>
__global__ __launch_bounds__(256) void gemm_kernel(const ushort* __restrict__ A,
                                                   const ushort* __restrict__ B,
                                                   const float* __restrict__ b_gen,
                                                   void* __restrict__ logits,
                                                   float* __restrict__ partials /*[NROW][500][2]*/) {
    __shared__ ushort sAB[4 * SLOT_BYTES / 2];    // 64 KB, 4 slots (epilogue reuses)

    // bijective XCD-chunk swizzle: 4000 blocks = 8 xcds x 500
    int orig = blockIdx.x;
    int wg = (orig & 7) * 500 + (orig >> 3);
    int mIdx = wg & 15;           // 16 m-tiles (16 consecutive wg share B panel, same XCD)
    int nIdx = wg >> 4;           // 250 n-tiles
    int m0 = mIdx * BM, n0 = nIdx * BN;
    int tid = threadIdx.x, wid = tid >> 6, lane = tid & 63;
    int wm = (wid >> 1) * 64, wn = (wid & 1) * 64;
    int lr = lane & 15, lg = lane >> 4;

    // staging sources (k-invariant). chunk-slot s holds row=s>>2, kc=(s&3)^((row>>1)&3)
    const ushort* gA[2]; const ushort* gB[2];
    uint32_t ldsOffA[2], ldsOffB[2];
    #pragma unroll
    for (int j = 0; j < 2; ++j) {
        int s = j * 256 + tid;
        int row = s >> 2;
        int kc = (s & 3) ^ ((row >> 1) & 3);
        gA[j] = A + (size_t)(m0 + row) * HS + kc * 8;
        gB[j] = B + (size_t)(n0 + row) * HS + kc * 8;
        ldsOffA[j] = (uint32_t)((j * 256 + wid * 64) * 16);             // wave-uniform dest
        ldsOffB[j] = (uint32_t)(B_REGION + (j * 256 + wid * 64) * 16);
    }

    // frag-read byte offsets within slot regions (swizzle verified 0-conflict in R2-R4)
    uint32_t kcs   = (uint32_t)((lg ^ ((lr >> 1) & 3)) * 16);
    uint32_t offAb = (uint32_t)(wm + lr) * 64 + kcs;                    // + mb*1024
    uint32_t offBb = B_REGION + (uint32_t)(wn + lr) * 64 + kcs;         // + nb*1024

    f32x4 acc[4][4];
    #pragma unroll
    for (int m = 0; m < 4; ++m)
        #pragma unroll
        for (int n = 0; n < 4; ++n) acc[m][n] = f32x4{0.f, 0.f, 0.f, 0.f};

#define STAGE(KT)                                                          \
    {                                                                      \
        char* sd = (char*)sAB + ((KT) & 3) * SLOT_BYTES;                   \
        int k0s = (KT) * BKT;                                              \
        _Pragma("unroll")                                                  \
        for (int j = 0; j < 2; ++j) {                                      \
            async16(gA[j] + k0s, sd + ldsOffA[j]);                         \
            async16(gB[j] + k0s, sd + ldsOffB[j]);                         \
        }                                                                  \
    }

    // prologue: stage slots 0,1,2 (12 loads in flight per thread)
    STAGE(0); STAGE(1); STAGE(2);

// Ledger: at top of tile kt, outstanding = S(kt),S(kt+1),S(kt+2) (12 loads);
// vmcnt(8) forces S(kt). Body stages S(kt+3) (slot (kt-1)&3 — its readers finished
// last tile, ordered by this barrier). Tail: NKT-2 -> vmcnt(4), NKT-1 -> vmcnt(0).
#define KTILE(KT, DOSTAGE, VMASM)                                                      \
    {                                                                                  \
        VMASM;                                                                         \
        asm volatile("s_barrier" ::: "memory");                                        \
        const char* sl = (const char*)sAB + ((KT) & 3) * SLOT_BYTES;                   \
        short8 av[4], bv[4];                                                           \
        _Pragma("unroll")                                                              \
        for (int nb = 0; nb < 4; ++nb)                                                 \
            bv[nb] = *(const short8*)(sl + offBb + nb * 1024);                         \
        _Pragma("unroll")                                                              \
        for (int mb = 0; mb < 4; ++mb)                                                 \
            av[mb] = *(const short8*)(sl + offAb + mb * 1024);                         \
        if (DOSTAGE) STAGE((KT) + 3);                                                  \
        asm volatile("s_waitcnt lgkmcnt(0)" ::: "memory");                             \
        __builtin_amdgcn_sched_barrier(0);                                             \
        __builtin_amdgcn_s_setprio(1);                                                 \
        _Pragma("unroll")                                                              \
        for (int mb = 0; mb < 4; ++mb)                                                 \
            _Pragma("unroll")                                                          \
            for (int nb = 0; nb < 4; ++nb)                                             \
                acc[mb][nb] = __builtin_amdgcn_mfma_f32_16x16x32_bf16(av[mb], bv[nb],  \
                                                                     acc[mb][nb], 0, 0, 0); \
        __builtin_amdgcn_s_setprio(0);                                                 \
    }

    for (int kt = 0; kt < NKT - 3; ++kt) {
        KTILE(kt, true, asm volatile("s_waitcnt vmcnt(8)" ::: "memory"));
    }
    KTILE(NKT - 3, false, asm volatile("s_waitcnt vmcnt(8)" ::: "memory"));
    KTILE(NKT - 2, false, asm volatile("s_waitcnt vmcnt(4)" ::: "memory"));
    KTILE(NKT - 1, false, asm volatile("s_waitcnt vmcnt(0)" ::: "memory"));
#undef KTILE
#undef STAGE

    // ---- epilogue ----
    asm volatile("s_barrier" ::: "memory");   // all waves done reading slots; reuse LDS

    float bg[4];
    #pragma unroll
    for (int nb = 0; nb < 4; ++nb) bg[nb] = b_gen[n0 + wn + nb * 16 + lr];
    int chunk = nIdx * 2 + (wid & 1);         // 500 chunks of 64 cols
    ushort* stile = sAB + wid * 4096;         // 64x64 bf16 per-wave repack region (8KB)

    #pragma unroll
    for (int mb = 0; mb < 4; ++mb) {
        #pragma unroll
        for (int r = 0; r < 4; ++r) {
            int rl = mb * 16 + lg * 4 + r;    // row within wave tile (0..63)
            int row = m0 + wm + rl;
            float v[4];
            float mx = -INFINITY;
            #pragma unroll
            for (int nb = 0; nb < 4; ++nb) {
                v[nb] = acc[mb][nb][r] + bg[nb];
                mx = fmaxf(mx, v[nb]);
            }
            if (BF16L) {
                #pragma unroll
                for (int nb = 0; nb < 4; ++nb) {
                    int cl = nb * 16 + lr;
                    int slot_w = (cl >> 3) ^ (rl & 7);
                    stile[rl * 64 + slot_w * 8 + (cl & 7)] = f2bf(v[nb]);
                }
            } else {
                float* outp = (float*)logits;
                #pragma unroll
                for (int nb = 0; nb < 4; ++nb)
                    outp[(size_t)row * VOC + n0 + wn + nb * 16 + lr] = v[nb];
            }
            for (int k = 8; k >= 1; k >>= 1) mx = fmaxf(mx, __shfl_xor(mx, k, 16));
            float se = 0.f;
            #pragma unroll
            for (int nb = 0; nb < 4; ++nb) se += __expf(v[nb] - mx);
            for (int k = 8; k >= 1; k >>= 1) se += __shfl_xor(se, k, 16);
            if (lr == 0) {
                float2 pv; pv.x = mx; pv.y = se;
                *(float2*)(partials + ((size_t)row * 500 + chunk) * 2) = pv;
            }
        }
    }
    if (BF16L) {
        ushort* Lbf = (ushort*)logits;
        #pragma unroll
        for (int rep = 0; rep < 8; ++rep) {
            int idx = rep * 64 + lane;
            int rl = idx >> 3, c8 = idx & 7;
            int slot_r = c8 ^ (rl & 7);
            short8 val = *(const short8*)(stile + rl * 64 + slot_r * 8);
            ushort* dst = Lbf + (size_t)(m0 + wm + rl) * VOC + n0 + wn + c8 * 8;
            *(short8*)dst = val;
        }
    }
}

// ---------------- combine per-chunk partials ----------------------------------------
__global__ __launch_bounds__(256) void reduce_kernel(const float* __restrict__ partials,
                                                     float* __restrict__ Ms,
                                                     float* __restrict__ Ss) {
    int wid = threadIdx.x >> 6, lane = threadIdx.x & 63;
    int row = blockIdx.x * 4 + wid;
    float m = -INFINITY, s = 0.f;
    for (int c = lane; c < 500; c += 64) {
        float2 p = *(const float2*)(partials + ((size_t)row * 500 + c) * 2);
        float nm = fmaxf(m, p.x);
        s = s * __expf(m - nm) + p.y * __expf(p.x - nm);
        m = nm;
    }
    for (int k = 32; k >= 1; k >>= 1) {
        float om = __shfl_xor(m, k, 64), os = __shfl_xor(s, k, 64);
        float nm = fmaxf(m, om);
        s = s * __expf(m - nm) + os * __expf(om - nm);
        m = nm;
    }
    if (lane == 0) { Ms[row] = m; Ss[row] = s; }
}

// ---------------- finalize: softmax scale, scatter-add p_c, log ---------------------
template <bool BF16L>
__global__ __launch_bounds__(256) void finalize_kernel(const int* __restrict__ src,
                                                       const float* __restrict__ p_c,
                                                       const float* __restrict__ cp,
                                                       const float* __restrict__ Ms,
                                                       const float* __restrict__ Ss,
                                                       const void* __restrict__ logits,
                                                       float* __restrict__ out) {
    int row = blockIdx.y;
    int c0 = blockIdx.x * 4096;
    int b = row & (BSZ - 1);
    __shared__ float addv[4096];
    int tid = threadIdx.x;
    for (int i = tid; i < 4096; i += 256) addv[i] = 0.f;
    __syncthreads();
    if (tid < SLEN) {
        int v = src[b * SLEN + tid];
        if (v >= c0 && v < c0 + 4096)
            atomicAdd(&addv[swz12(v - c0)], p_c[row * SLEN + tid]);
    }
    __syncthreads();
    int col = c0 + tid * 16;
    if (col >= VOC) return;
    float M = Ms[row];
    float g = (1.f - cp[row]) / Ss[row];
    float L[16];
    if (BF16L) {
        const ushort* lb = (const ushort*)logits + (size_t)row * VOC + col;
        short8 a = *(const short8*)lb;
        short8 c = *(const short8*)(lb + 8);
        for (int i = 0; i < 8; ++i) { L[i] = bf2f((ushort)a[i]); L[8 + i] = bf2f((ushort)c[i]); }
    } else {
        const float* lf = (const float*)logits + (size_t)row * VOC + col;
        for (int i = 0; i < 4; ++i) {
            float4 v = *(const float4*)(lf + i * 4);
            L[i * 4 + 0] = v.x; L[i * 4 + 1] = v.y; L[i * 4 + 2] = v.z; L[i * 4 + 3] = v.w;
        }
    }
    float res[16];
    for (int i = 0; i < 16; ++i) {
        float p = __expf(L[i] - M) * g + addv[swz12(tid * 16 + i)];
        res[i] = __logf(p) + C_CONST_F;
    }
    float* op = out + (size_t)row * VOC + col;
    for (int i = 0; i < 4; ++i) {
        float4 v;
        v.x = res[i * 4 + 0]; v.y = res[i * 4 + 1]; v.z = res[i * 4 + 2]; v.w = res[i * 4 + 3];
        *(float4*)(op + i * 4) = v;
    }
}

extern "C" void kernel_launch(void* const* d_in, const int* in_sizes, int n_in,
                              void* d_out, int out_size, void* d_ws, size_t ws_size,
                              hipStream_t stream) {
    const float* hidden  = (const float*)d_in[0];
    const float* context = (const float*)d_in[1];
    const int*   src     = (const int*)d_in[2];
    const float* W_gen   = (const float*)d_in[3];
    const float* b_gen   = (const float*)d_in[4];
    const float* w_copy  = (const float*)d_in[5];
    const float* b_copy  = (const float*)d_in[6];
    float* out = (float*)d_out;
    char* ws = (char*)d_ws;

    float*  cp       = (float*)(ws);                    // 8 KB
    float*  p_c      = (float*)(ws + 8192);             // 512 KB
    float*  Ms       = (float*)(ws + 532480);
    float*  Ss       = (float*)(ws + 540672);
    float*  partials = (float*)(ws + 548864);           // 8.192 MB
    ushort* Abf      = (ushort*)(ws + 8740864);         // 4 MB
    ushort* Wbf      = (ushort*)(ws + 12935168);        // 65.5 MB -> ends 78471168
    ushort* Lbf      = (ushort*)(ws + 78471168);        // 131 MB  -> ends 209543168
    const size_t NEED_BF16 = 209543168;

    gate_kernel<<<NROW / 4, 256, 0, stream>>>(hidden, w_copy, b_copy, cp);
    attn_kernel<<<NROW, 256, 0, stream>>>(hidden, context, src, cp, p_c);
    cvt_kernel<<<(NROW * HS / 4) / 256, 256, 0, stream>>>(hidden, Abf, NROW * HS / 4);
    cvt_kernel<<<(VOC * HS / 4) / 256, 256, 0, stream>>>(W_gen, Wbf, VOC * HS / 4);

    int ggrid = (NROW / BM) * (VOC / BN);   // 16 * 250 = 4000
    dim3 fgrid(8, NROW);
    if (ws_size >= NEED_BF16) {
        gemm_kernel<true><<<ggrid, 256, 0, stream>>>(Abf, Wbf, b_gen, Lbf, partials);
        reduce_kernel<<<NROW / 4, 256, 0, stream>>>(partials, Ms, Ss);
        finalize_kernel<true><<<fgrid, 256, 0, stream>>>(src, p_c, cp, Ms, Ss, Lbf, out);
    } else {
        gemm_kernel<false><<<ggrid, 256, 0, stream>>>(Abf, Wbf, b_gen, out, partials);
        reduce_kernel<<<NROW / 4, 256, 0, stream>>>(partials, Ms, Ss);
        finalize_kernel<false><<<fgrid, 256, 0, stream>>>(src, p_c, cp, Ms, Ss, out, out);
    }
}

// Round 7
// 334.614 us; speedup vs baseline: 1.5225x; 1.1523x over previous
//
#include <hip/hip_runtime.h>
#include <hip/hip_bf16.h>
#include <stdint.h>

#define TLEN 64
#define BSZ 32
#define SLEN 64
#define HS 1024
#define VOC 32000
#define NROW (TLEN*BSZ)   // 2048
#define C_CONST_F 0.1712209f

// GEMM geometry: 256x256 tile, 8 waves, 4-slot K-pipeline, BK=32/slot (R3-verified)
#define BM 256
#define BN 256
#define BKT 32
#define NKT (HS/BKT)          // 32 K-tiles
#define SLOT_BYTES 32768      // A 16KB + B 16KB
#define B_REGION 16384        // byte offset of B within slot

typedef __attribute__((ext_vector_type(8))) short short8;
typedef __attribute__((ext_vector_type(4))) float f32x4;

static __device__ __forceinline__ ushort f2bf(float f) {
    uint32_t u = __builtin_bit_cast(uint32_t, f);
    uint32_t r = (u + 0x7fffu + ((u >> 16) & 1u)) >> 16;
    return (ushort)r;
}
static __device__ __forceinline__ float bf2f(ushort u) {
    uint32_t v = ((uint32_t)u) << 16;
    return __builtin_bit_cast(float, v);
}
static __device__ __forceinline__ void async16(const void* g, void* lds) {
    __builtin_amdgcn_global_load_lds(
        (const __attribute__((address_space(1))) void*)g,
        (__attribute__((address_space(3))) void*)lds, 16, 0, 0);
}
static __device__ __forceinline__ int swz12(int e) { return e ^ (((e >> 4) & 15) << 1); }

// ---------------- copy attention + fused copy gate ----------------------------------
__global__ __launch_bounds__(256) void attn_kernel(const float* __restrict__ hidden,
                                                   const float* __restrict__ context,
                                                   const int* __restrict__ src,
                                                   const float* __restrict__ w_copy,
                                                   const float* __restrict__ b_copy,
                                                   float* __restrict__ cp,
                                                   float* __restrict__ p_c) {
    int row = blockIdx.x;           // t*BSZ + b
    int b = row & (BSZ - 1);
    int tid = threadIdx.x, wid = tid >> 6, lane = tid & 63;
    __shared__ float hrow[HS];
    __shared__ float sc[SLEN];
    __shared__ float wred[4];
    __shared__ float cp_s;
    float4 h4 = *(const float4*)(hidden + (size_t)row * HS + tid * 4);
    *(float4*)(hrow + tid * 4) = h4;
    // gate partial (reuses the row load)
    float4 w4 = *(const float4*)(w_copy + tid * 4);
    float g = h4.x * w4.x + h4.y * w4.y + h4.z * w4.z + h4.w * w4.w;
    for (int m = 32; m >= 1; m >>= 1) g += __shfl_xor(g, m, 64);
    if (lane == 0) wred[wid] = g;
    __syncthreads();                 // hrow + wred ready
    if (tid == 0) {
        float s = 1.f / (1.f + expf(-(wred[0] + wred[1] + wred[2] + wred[3] + b_copy[0])));
        cp_s = s;
        cp[row] = s;
    }
    for (int j = 0; j < 16; ++j) {
        int s = wid * 16 + j;
        const float* c = context + ((size_t)s * BSZ + b) * HS;
        float acc = 0.f;
        for (int i = 0; i < 4; ++i) {
            int off = (i * 64 + lane) * 4;
            float4 cv = *(const float4*)(c + off);
            float4 hv = *(const float4*)(hrow + off);
            acc += cv.x * hv.x + cv.y * hv.y + cv.z * hv.z + cv.w * hv.w;
        }
        for (int m = 32; m >= 1; m >>= 1) acc += __shfl_xor(acc, m, 64);
        if (lane == 0) sc[s] = acc;
    }
    __syncthreads();                 // sc + cp_s ready
    if (tid < SLEN) {
        float v = sc[tid];
        if (src[b * SLEN + tid] == 0) v = -INFINITY;   // PAD mask
        float m = v;
        for (int k = 32; k >= 1; k >>= 1) m = fmaxf(m, __shfl_xor(m, k, 64));
        float e = expf(v - m);
        float ssum = e;
        for (int k = 32; k >= 1; k >>= 1) ssum += __shfl_xor(ssum, k, 64);
        p_c[row * SLEN + tid] = (e / ssum) * cp_s;
    }
}

// ---------------- f32 -> bf16 conversion (hidden + W_gen in one launch) -------------
// dst = Abf (contiguous with Wbf in ws). Boundary is block-aligned (2048 blocks of A).
__global__ __launch_bounds__(256) void cvt_kernel(const float* __restrict__ hidden,
                                                  const float* __restrict__ W_gen,
                                                  ushort* __restrict__ dst) {
    const int A4 = NROW * HS / 4;
    int i = blockIdx.x * 256 + threadIdx.x;
    float4 v = (i < A4) ? ((const float4*)hidden)[i] : ((const float4*)W_gen)[i - A4];
    ushort4 o;
    o.x = f2bf(v.x); o.y = f2bf(v.y); o.z = f2bf(v.z); o.w = f2bf(v.w);
    ((ushort4*)dst)[i] = o;
}

// ---------------- main GEMM: logits = A(2048x1024) * B(32000x1024)^T + b_gen --------
// 256x256 tile, 8 waves (2Mx4N), 4-slot LDS pipeline (XOR-swizzled, counted vmcnt,
// 1 barrier/tile — R3-verified 177us schedule). x4 unroll (slot indices const),
// setprio removed (m190: hurts lockstep GEMM).
template <bool BF16L>
__global__ __launch_bounds__(512, 2) void gemm_kernel(const ushort* __restrict__ A,
                                                      const ushort* __restrict__ B,
                                                      const float* __restrict__ b_gen,
                                                      void* __restrict__ logits,
                                                      float* __restrict__ partials /*[NROW][500][2]*/) {
    __shared__ ushort sAB[4 * SLOT_BYTES / 2];    // 128 KB, 4 slots

    // bijective XCD-chunk swizzle: 1000 blocks = 8 xcds x 125
    int orig = blockIdx.x;
    int wg = (orig & 7) * 125 + (orig >> 3);
    int mIdx = wg & 7;            // 8 m-tiles
    int nIdx = wg >> 3;           // 125 n-tiles
    int m0 = mIdx * BM, n0 = nIdx * BN;
    int tid = threadIdx.x, wid = tid >> 6, lane = tid & 63;
    int wm = (wid >> 2) * 128, wn = (wid & 3) * 64;
    int lr = lane & 15, lg = lane >> 4;

    // staging sources (k-invariant). chunk s (16B) holds row=s>>2, kc=(s&3)^((row>>1)&3)
    const ushort* gA[2]; const ushort* gB[2];
    uint32_t ldsOffA[2], ldsOffB[2];
    #pragma unroll
    for (int j = 0; j < 2; ++j) {
        int s = j * 512 + tid;
        int row = s >> 2;
        int kc = (s & 3) ^ ((row >> 1) & 3);
        gA[j] = A + (size_t)(m0 + row) * HS + kc * 8;
        gB[j] = B + (size_t)(n0 + row) * HS + kc * 8;
        ldsOffA[j] = (uint32_t)((j * 512 + wid * 64) * 16);             // wave-uniform dest
        ldsOffB[j] = (uint32_t)(B_REGION + (j * 512 + wid * 64) * 16);
    }

    // frag-read byte offsets within slot regions (0-conflict, verified R2-R6)
    uint32_t kcs   = (uint32_t)((lg ^ ((lr >> 1) & 3)) * 16);
    uint32_t offAb = (uint32_t)(wm + lr) * 64 + kcs;                    // + mb*1024
    uint32_t offBb = B_REGION + (uint32_t)(wn + lr) * 64 + kcs;         // + nb*1024

    f32x4 acc[8][4];
    #pragma unroll
    for (int m = 0; m < 8; ++m)
        #pragma unroll
        for (int n = 0; n < 4; ++n) acc[m][n] = f32x4{0.f, 0.f, 0.f, 0.f};

#define STAGE(KT)                                                          \
    {                                                                      \
        char* sd = (char*)sAB + ((KT) & 3) * SLOT_BYTES;                   \
        int k0s = (KT) * BKT;                                              \
        _Pragma("unroll")                                                  \
        for (int j = 0; j < 2; ++j) {                                      \
            async16(gA[j] + k0s, sd + ldsOffA[j]);                         \
            async16(gB[j] + k0s, sd + ldsOffB[j]);                         \
        }                                                                  \
    }

#define PHASE_BODY(KT, DOSTAGE)                                                        \
    {                                                                                  \
        const char* sl = (const char*)sAB + ((KT) & 3) * SLOT_BYTES;                   \
        short8 af[8], bv[4];                                                           \
        _Pragma("unroll")                                                              \
        for (int mb = 0; mb < 8; ++mb)                                                 \
            af[mb] = *(const short8*)(sl + offAb + mb * 1024);                         \
        _Pragma("unroll")                                                              \
        for (int nb = 0; nb < 4; ++nb)                                                 \
            bv[nb] = *(const short8*)(sl + offBb + nb * 1024);                         \
        if (DOSTAGE) STAGE((KT) + 3);                                                  \
        _Pragma("unroll")                                                              \
        for (int mb = 0; mb < 8; ++mb)                                                 \
            _Pragma("unroll")                                                          \
            for (int nb = 0; nb < 4; ++nb)                                             \
                acc[mb][nb] = __builtin_amdgcn_mfma_f32_16x16x32_bf16(af[mb], bv[nb],  \
                                                                     acc[mb][nb], 0, 0, 0); \
    }

#define GATE8 asm volatile("s_waitcnt vmcnt(8)\n\ts_barrier" ::: "memory")

    // prologue: stage slots 0,1,2 (12 loads in flight)
    STAGE(0); STAGE(1); STAGE(2);

    // main loop, x4 unrolled so slot indices are compile-time constants.
    // Ledger: at each gate, outstanding = S(kt),S(kt+1),S(kt+2) (12); vmcnt(8) forces S(kt).
    for (int kb = 0; kb < 7; ++kb) {
        int kt = kb * 4;
        GATE8; PHASE_BODY(kt + 0, true);
        GATE8; PHASE_BODY(kt + 1, true);
        GATE8; PHASE_BODY(kt + 2, true);
        GATE8; PHASE_BODY(kt + 3, true);
    }
    GATE8; PHASE_BODY(28, true);    // stages S31 (last)
    GATE8; PHASE_BODY(29, false);
    asm volatile("s_waitcnt vmcnt(4)\n\ts_barrier" ::: "memory");
    PHASE_BODY(30, false);
    asm volatile("s_waitcnt vmcnt(0)\n\ts_barrier" ::: "memory");
    PHASE_BODY(31, false);
#undef PHASE_BODY
#undef STAGE
#undef GATE8

    // ---- epilogue ----
    asm volatile("s_barrier" ::: "memory");   // all waves done reading slots; reuse LDS

    float bg[4];
    #pragma unroll
    for (int nb = 0; nb < 4; ++nb) bg[nb] = b_gen[n0 + wn + nb * 16 + lr];
    int chunk = nIdx * 4 + (wid & 3);         // 500 chunks of 64 cols
    ushort* stile = sAB + wid * 8192;         // 128x64 bf16 per-wave repack region (16KB)

    #pragma unroll
    for (int mb = 0; mb < 8; ++mb) {
        #pragma unroll
        for (int r = 0; r < 4; ++r) {
            int rl = mb * 16 + lg * 4 + r;    // row within wave tile (0..127)
            int row = m0 + wm + rl;
            float v[4];
            float mx = -INFINITY;
            #pragma unroll
            for (int nb = 0; nb < 4; ++nb) {
                v[nb] = acc[mb][nb][r] + bg[nb];
                mx = fmaxf(mx, v[nb]);
            }
            if (BF16L) {
                #pragma unroll
                for (int nb = 0; nb < 4; ++nb) {
                    int cl = nb * 16 + lr;
                    int slot_w = (cl >> 3) ^ (rl & 7);
                    stile[rl * 64 + slot_w * 8 + (cl & 7)] = f2bf(v[nb]);
                }
            } else {
                float* outp = (float*)logits;
                #pragma unroll
                for (int nb = 0; nb < 4; ++nb)
                    outp[(size_t)row * VOC + n0 + wn + nb * 16 + lr] = v[nb];
            }
            for (int k = 8; k >= 1; k >>= 1) mx = fmaxf(mx, __shfl_xor(mx, k, 16));
            float se = 0.f;
            #pragma unroll
            for (int nb = 0; nb < 4; ++nb) se += __expf(v[nb] - mx);
            for (int k = 8; k >= 1; k >>= 1) se += __shfl_xor(se, k, 16);
            if (lr == 0) {
                float2 pv; pv.x = mx; pv.y = se;
                *(float2*)(partials + ((size_t)row * 500 + chunk) * 2) = pv;
            }
        }
    }
    if (BF16L) {
        ushort* Lbf = (ushort*)logits;
        #pragma unroll
        for (int rep = 0; rep < 16; ++rep) {
            int idx = rep * 64 + lane;
            int rl = idx >> 3, c8 = idx & 7;
            int slot_r = c8 ^ (rl & 7);
            short8 val = *(const short8*)(stile + rl * 64 + slot_r * 8);
            ushort* dst = Lbf + (size_t)(m0 + wm + rl) * VOC + n0 + wn + c8 * 8;
            *(short8*)dst = val;
        }
    }
}

// ---------------- combine per-chunk partials ----------------------------------------
__global__ __launch_bounds__(256) void reduce_kernel(const float* __restrict__ partials,
                                                     float* __restrict__ Ms,
                                                     float* __restrict__ Ss) {
    int wid = threadIdx.x >> 6, lane = threadIdx.x & 63;
    int row = blockIdx.x * 4 + wid;
    float m = -INFINITY, s = 0.f;
    for (int c = lane; c < 500; c += 64) {
        float2 p = *(const float2*)(partials + ((size_t)row * 500 + c) * 2);
        float nm = fmaxf(m, p.x);
        s = s * __expf(m - nm) + p.y * __expf(p.x - nm);
        m = nm;
    }
    for (int k = 32; k >= 1; k >>= 1) {
        float om = __shfl_xor(m, k, 64), os = __shfl_xor(s, k, 64);
        float nm = fmaxf(m, om);
        s = s * __expf(m - nm) + os * __expf(om - nm);
        m = nm;
    }
    if (lane == 0) { Ms[row] = m; Ss[row] = s; }
}

// ---------------- finalize: softmax scale, scatter-add p_c, log ---------------------
template <bool BF16L>
__global__ __launch_bounds__(256) void finalize_kernel(const int* __restrict__ src,
                                                       const float* __restrict__ p_c,
                                                       const float* __restrict__ cp,
                                                       const float* __restrict__ Ms,
                                                       const float* __restrict__ Ss,
                                                       const void* __restrict__ logits,
                                                       float* __restrict__ out) {
    int row = blockIdx.y;
    int c0 = blockIdx.x * 4096;
    int b = row & (BSZ - 1);
    __shared__ float addv[4096];
    int tid = threadIdx.x;
    for (int i = tid; i < 4096; i += 256) addv[i] = 0.f;
    __syncthreads();
    if (tid < SLEN) {
        int v = src[b * SLEN + tid];
        if (v >= c0 && v < c0 + 4096)
            atomicAdd(&addv[swz12(v - c0)], p_c[row * SLEN + tid]);
    }
    __syncthreads();
    int col = c0 + tid * 16;
    if (col >= VOC) return;
    float M = Ms[row];
    float g = (1.f - cp[row]) / Ss[row];
    float L[16];
    if (BF16L) {
        const ushort* lb = (const ushort*)logits + (size_t)row * VOC + col;
        short8 a = *(const short8*)lb;
        short8 c = *(const short8*)(lb + 8);
        for (int i = 0; i < 8; ++i) { L[i] = bf2f((ushort)a[i]); L[8 + i] = bf2f((ushort)c[i]); }
    } else {
        const float* lf = (const float*)logits + (size_t)row * VOC + col;
        for (int i = 0; i < 4; ++i) {
            float4 v = *(const float4*)(lf + i * 4);
            L[i * 4 + 0] = v.x; L[i * 4 + 1] = v.y; L[i * 4 + 2] = v.z; L[i * 4 + 3] = v.w;
        }
    }
    float res[16];
    for (int i = 0; i < 16; ++i) {
        float p = __expf(L[i] - M) * g + addv[swz12(tid * 16 + i)];
        res[i] = __logf(p) + C_CONST_F;
    }
    float* op = out + (size_t)row * VOC + col;
    for (int i = 0; i < 4; ++i) {
        float4 v;
        v.x = res[i * 4 + 0]; v.y = res[i * 4 + 1]; v.z = res[i * 4 + 2]; v.w = res[i * 4 + 3];
        *(float4*)(op + i * 4) = v;
    }
}

extern "C" void kernel_launch(void* const* d_in, const int* in_sizes, int n_in,
                              void* d_out, int out_size, void* d_ws, size_t ws_size,
                              hipStream_t stream) {
    const float* hidden  = (const float*)d_in[0];
    const float* context = (const float*)d_in[1];
    const int*   src     = (const int*)d_in[2];
    const float* W_gen   = (const float*)d_in[3];
    const float* b_gen   = (const float*)d_in[4];
    const float* w_copy  = (const float*)d_in[5];
    const float* b_copy  = (const float*)d_in[6];
    float* out = (float*)d_out;
    char* ws = (char*)d_ws;

    float*  cp       = (float*)(ws);                    // 8 KB
    float*  p_c      = (float*)(ws + 8192);             // 512 KB
    float*  Ms       = (float*)(ws + 532480);
    float*  Ss       = (float*)(ws + 540672);
    float*  partials = (float*)(ws + 548864);           // 8.192 MB
    ushort* Abf      = (ushort*)(ws + 8740864);         // 4 MB   (contiguous with Wbf)
    ushort* Wbf      = (ushort*)(ws + 12935168);        // 65.5 MB -> ends 78471168
    ushort* Lbf      = (ushort*)(ws + 78471168);        // 131 MB  -> ends 209543168
    const size_t NEED_BF16 = 209543168;
    (void)Wbf;

    attn_kernel<<<NROW, 256, 0, stream>>>(hidden, context, src, w_copy, b_copy, cp, p_c);
    cvt_kernel<<<(NROW * HS / 4 + VOC * HS / 4) / 256, 256, 0, stream>>>(hidden, W_gen, Abf);

    int ggrid = (NROW / BM) * (VOC / BN);   // 8 * 125 = 1000
    dim3 fgrid(8, NROW);
    const ushort* Wb = (const ushort*)(ws + 12935168);
    if (ws_size >= NEED_BF16) {
        gemm_kernel<true><<<ggrid, 512, 0, stream>>>(Abf, Wb, b_gen, Lbf, partials);
        reduce_kernel<<<NROW / 4, 256, 0, stream>>>(partials, Ms, Ss);
        finalize_kernel<true><<<fgrid, 256, 0, stream>>>(src, p_c, cp, Ms, Ss, Lbf, out);
    } else {
        gemm_kernel<false><<<ggrid, 512, 0, stream>>>(Abf, Wb, b_gen, out, partials);
        reduce_kernel<<<NROW / 4, 256, 0, stream>>>(partials, Ms, Ss);
        finalize_kernel<false><<<fgrid, 256, 0, stream>>>(src, p_c, cp, Ms, Ss, out, out);
    }
}